// Round 1
// baseline (761.714 us; speedup 1.0000x reference)
//
#include <hip/hip_runtime.h>
#include <hip/hip_bf16.h>
#include <stdint.h>
#include <math.h>

#define NR 16384
#define DIM 768
#define KEPS 1e-8f

#define BM 128          // rows per block / cols per col-tile
#define BK 64           // staged K per tile
#define NSPLIT 4        // column splits (grid.y)
#define CPS (NR / NSPLIT)     // 4096 cols per split
#define CT_PER (CPS / BM)     // 32 col tiles per block
#define KT (DIM / BK)         // 12 k-tiles

typedef __attribute__((ext_vector_type(4))) float f32x4;
typedef __attribute__((ext_vector_type(8))) short bf16x8;

__device__ inline ushort f2bf(float f) {
    union { float f; uint32_t u; } v; v.f = f;
    uint32_t u = v.u;
    return (ushort)((u + 0x7FFFu + ((u >> 16) & 1u)) >> 16);
}

__device__ inline void gload16(const ushort* g, const ushort* l) {
    __builtin_amdgcn_global_load_lds(
        (const __attribute__((address_space(1))) void*)g,
        (__attribute__((address_space(3))) void*)l,
        16, 0, 0);
}

// ---------------- Kernel 1: row L2-normalize, fp32 -> bf16 -------------------
__global__ __launch_bounds__(256) void k_norm(const float* __restrict__ X,
                                              ushort* __restrict__ Xn) {
    const int wid = threadIdx.x >> 6, lane = threadIdx.x & 63;
    const int row = blockIdx.x * 4 + wid;
    const float4* xr = (const float4*)(X + (size_t)row * DIM) + lane * 3;
    float4 a = xr[0], b = xr[1], c = xr[2];
    float s = a.x*a.x + a.y*a.y + a.z*a.z + a.w*a.w
            + b.x*b.x + b.y*b.y + b.z*b.z + b.w*b.w
            + c.x*c.x + c.y*c.y + c.z*c.z + c.w*c.w;
#pragma unroll
    for (int m = 32; m >= 1; m >>= 1) s += __shfl_xor(s, m);
    const float rn = 1.0f / fmaxf(sqrtf(s), KEPS);
    float v[12] = {a.x,a.y,a.z,a.w,b.x,b.y,b.z,b.w,c.x,c.y,c.z,c.w};
    uint32_t p[6];
#pragma unroll
    for (int i = 0; i < 6; ++i)
        p[i] = (uint32_t)f2bf(v[2*i]*rn) | ((uint32_t)f2bf(v[2*i+1]*rn) << 16);
    uint2* dst = (uint2*)(Xn + (size_t)row * DIM + lane * 12);
    dst[0] = make_uint2(p[0], p[1]);
    dst[1] = make_uint2(p[2], p[3]);
    dst[2] = make_uint2(p[4], p[5]);
}

// ------------- Kernel 2: fused Xn*Xn^T row-max (diag masked) -----------------
__global__ __launch_bounds__(256) void k_maxdot(const ushort* __restrict__ Xn,
                                                float* __restrict__ pmax) {
    __shared__ ushort lA[2][BM * BK];
    __shared__ ushort lB[2][BM * BK];
    const int tid  = threadIdx.x;
    const int lane = tid & 63, wid = tid >> 6;
    const int wr = wid >> 1, wc = wid & 1;
    const int l15 = lane & 15, lhi = lane >> 4;
    const int rb = blockIdx.x;
    const int cs = blockIdx.y;
    const int rowbase = rb * BM;

    // staging decomposition: per issue, thread covers 8 ushort at LDS elem tid*8
    const int s_row  = tid >> 3;      // row within 32-row chunk
    const int s_slot = tid & 7;       // 8-elem slot within 64-elem row

    float rmax[4][4];
#pragma unroll
    for (int i = 0; i < 4; ++i)
#pragma unroll
        for (int j = 0; j < 4; ++j) rmax[i][j] = -2.0f;

    for (int ct = 0; ct < CT_PER; ++ct) {
        const int colbase = cs * CPS + ct * BM;

        f32x4 acc[4][4];
        const f32x4 z = {0.f, 0.f, 0.f, 0.f};
#pragma unroll
        for (int i = 0; i < 4; ++i)
#pragma unroll
            for (int j = 0; j < 4; ++j) acc[i][j] = z;

        auto STAGE = [&](int buf, int kt) {
            // XOR-swizzled source so linear global_load_lds dest + swizzled
            // ds_read agree (slot' = slot ^ (row&7)); 4 issues of 32 rows each.
#pragma unroll
            for (int it = 0; it < 4; ++it) {
                const int r = it * 32 + s_row;
                const size_t koff = (size_t)kt * BK + (size_t)((s_slot ^ (r & 7)) << 3);
                const ushort* gA = Xn + (size_t)(rowbase + r) * DIM + koff;
                const ushort* gB = Xn + (size_t)(colbase + r) * DIM + koff;
                const ushort* dA = &lA[buf][it * 2048 + wid * 512];
                const ushort* dB = &lB[buf][it * 2048 + wid * 512];
                gload16(gA, dA);
                gload16(gB, dB);
            }
        };

        STAGE(0, 0);
        for (int kt = 0; kt < KT; ++kt) {
            __syncthreads();                       // buf[kt&1] ready
            if (kt + 1 < KT) STAGE((kt + 1) & 1, kt + 1);
            const ushort* A = lA[kt & 1];
            const ushort* B = lB[kt & 1];
#pragma unroll
            for (int ks = 0; ks < 2; ++ks) {
                bf16x8 af[4], bg[4];
#pragma unroll
                for (int mf = 0; mf < 4; ++mf) {
                    const int r = wr * 64 + mf * 16 + l15;
                    const int slot = (ks * 4 + lhi) ^ (r & 7);
                    af[mf] = *(const bf16x8*)(A + r * BK + slot * 8);
                }
#pragma unroll
                for (int nf = 0; nf < 4; ++nf) {
                    const int r = wc * 64 + nf * 16 + l15;
                    const int slot = (ks * 4 + lhi) ^ (r & 7);
                    bg[nf] = *(const bf16x8*)(B + r * BK + slot * 8);
                }
#pragma unroll
                for (int mf = 0; mf < 4; ++mf)
#pragma unroll
                    for (int nf = 0; nf < 4; ++nf)
                        acc[mf][nf] = __builtin_amdgcn_mfma_f32_16x16x32_bf16(
                            af[mf], bg[nf], acc[mf][nf], 0, 0, 0);
            }
        }

        // epilogue: fold this 128x128 tile into running row-max
        const bool diag = (rowbase == colbase);
        if (diag) {
#pragma unroll
            for (int mf = 0; mf < 4; ++mf)
#pragma unroll
                for (int nf = 0; nf < 4; ++nf)
#pragma unroll
                    for (int rr = 0; rr < 4; ++rr) {
                        const int r = wr * 64 + mf * 16 + lhi * 4 + rr;
                        const int c = wc * 64 + nf * 16 + l15;
                        float vv = acc[mf][nf][rr];
                        if (r == c) vv = -1.0f;   // reference diagonal mask
                        rmax[mf][rr] = fmaxf(rmax[mf][rr], vv);
                    }
        } else {
#pragma unroll
            for (int mf = 0; mf < 4; ++mf)
#pragma unroll
                for (int nf = 0; nf < 4; ++nf)
#pragma unroll
                    for (int rr = 0; rr < 4; ++rr)
                        rmax[mf][rr] = fmaxf(rmax[mf][rr], acc[mf][nf][rr]);
        }
    }

    // reduce row-max across the 16 lanes sharing lhi, then write
#pragma unroll
    for (int mf = 0; mf < 4; ++mf)
#pragma unroll
        for (int rr = 0; rr < 4; ++rr) {
            float v = rmax[mf][rr];
            v = fmaxf(v, __shfl_xor(v, 1));
            v = fmaxf(v, __shfl_xor(v, 2));
            v = fmaxf(v, __shfl_xor(v, 4));
            v = fmaxf(v, __shfl_xor(v, 8));
            rmax[mf][rr] = v;
        }
    if (l15 == 0) {
#pragma unroll
        for (int mf = 0; mf < 4; ++mf)
#pragma unroll
            for (int rr = 0; rr < 4; ++rr) {
                const int r = rowbase + wr * 64 + mf * 16 + lhi * 4 + rr;
                pmax[(size_t)cs * NR + r] = rmax[mf][rr];
            }
    }
}

// ---------------- Kernel 3: merge partials, compute loss ---------------------
__global__ __launch_bounds__(256) void k_loss(const float* __restrict__ pmax,
                                              float* __restrict__ out) {
    float local = 0.0f;
    for (int r = threadIdx.x; r < NR; r += 256) {
        float m = pmax[r];
#pragma unroll
        for (int s = 1; s < NSPLIT; ++s) m = fmaxf(m, pmax[(size_t)s * NR + r]);
        const float d = sqrtf(fmaxf(2.0f - 2.0f * m, 0.0f));
        local += logf(d + KEPS);
    }
#pragma unroll
    for (int m = 32; m >= 1; m >>= 1) local += __shfl_xor(local, m);
    __shared__ float red[4];
    const int lane = threadIdx.x & 63, wid = threadIdx.x >> 6;
    if (lane == 0) red[wid] = local;
    __syncthreads();
    if (threadIdx.x == 0)
        out[0] = -(red[0] + red[1] + red[2] + red[3]) / (float)NR;
}

extern "C" void kernel_launch(void* const* d_in, const int* in_sizes, int n_in,
                              void* d_out, int out_size, void* d_ws, size_t ws_size,
                              hipStream_t stream) {
    const float* X = (const float*)d_in[0];
    float* out = (float*)d_out;
    ushort* Xn = (ushort*)d_ws;                                  // 24 MiB bf16
    float* pmax = (float*)((char*)d_ws + (size_t)NR * DIM * 2);  // 4*16384 f32

    k_norm<<<NR / 4, 256, 0, stream>>>(X, Xn);
    dim3 g2(NR / BM, NSPLIT);
    k_maxdot<<<g2, 256, 0, stream>>>(Xn, pmax);
    k_loss<<<1, 256, 0, stream>>>(pmax, out);
}

// Round 2
// 417.093 us; speedup vs baseline: 1.8262x; 1.8262x over previous
//
#include <hip/hip_runtime.h>
#include <hip/hip_bf16.h>
#include <stdint.h>
#include <math.h>

#define NR 16384
#define DIM 768
#define KEPS 1e-8f

#define BM 128          // tile edge
#define BK 64           // staged K per tile
#define NB (NR / BM)    // 128 row/col blocks
#define KT (DIM / BK)   // 12 k-tiles
#define NTILES (NB * (NB + 1) / 2)   // 8256 upper-triangle tiles

typedef __attribute__((ext_vector_type(4))) float f32x4;
typedef _Float16 f16x8 __attribute__((ext_vector_type(8)));

__device__ inline uint32_t fkey(float f) {
    union { float f; uint32_t u; } v; v.f = f;
    return (v.u & 0x80000000u) ? ~v.u : (v.u | 0x80000000u);
}
__device__ inline float unkey(uint32_t k) {
    union { uint32_t u; float f; } v;
    v.u = (k & 0x80000000u) ? (k ^ 0x80000000u) : ~k;
    return v.f;
}

__device__ inline void gload16(const ushort* g, const ushort* l) {
    __builtin_amdgcn_global_load_lds(
        (const __attribute__((address_space(1))) void*)g,
        (__attribute__((address_space(3))) void*)l,
        16, 0, 0);
}

// ---------------- Kernel 1: row L2-normalize, fp32 -> fp16 -------------------
__global__ __launch_bounds__(256) void k_norm(const float* __restrict__ X,
                                              ushort* __restrict__ Xn) {
    const int wid = threadIdx.x >> 6, lane = threadIdx.x & 63;
    const int row = blockIdx.x * 4 + wid;
    const float4* xr = (const float4*)(X + (size_t)row * DIM) + lane * 3;
    float4 a = xr[0], b = xr[1], c = xr[2];
    float s = a.x*a.x + a.y*a.y + a.z*a.z + a.w*a.w
            + b.x*b.x + b.y*b.y + b.z*b.z + b.w*b.w
            + c.x*c.x + c.y*c.y + c.z*c.z + c.w*c.w;
#pragma unroll
    for (int m = 32; m >= 1; m >>= 1) s += __shfl_xor(s, m);
    const float rn = 1.0f / fmaxf(sqrtf(s), KEPS);
    float v[12] = {a.x,a.y,a.z,a.w,b.x,b.y,b.z,b.w,c.x,c.y,c.z,c.w};
    uint32_t p[6];
#pragma unroll
    for (int i = 0; i < 6; ++i) {
        union { _Float16 h[2]; uint32_t u; } pk;
        pk.h[0] = (_Float16)(v[2*i] * rn);
        pk.h[1] = (_Float16)(v[2*i+1] * rn);
        p[i] = pk.u;
    }
    uint2* dst = (uint2*)(Xn + (size_t)row * DIM + lane * 12);
    dst[0] = make_uint2(p[0], p[1]);
    dst[1] = make_uint2(p[2], p[3]);
    dst[2] = make_uint2(p[4], p[5]);
}

// ---------------- Kernel 1b: init nn-max keys --------------------------------
__global__ __launch_bounds__(256) void k_init(uint32_t* __restrict__ nnkey) {
    nnkey[blockIdx.x * 256 + threadIdx.x] = fkey(-2.0f);
}

// -------- Kernel 2: upper-triangle Xn*Xn^T tile, fold row+col max ------------
__global__ __launch_bounds__(256) void k_maxdot(const ushort* __restrict__ Xn,
                                                uint32_t* __restrict__ nnkey) {
    __shared__ ushort lA[2][BM * BK];
    __shared__ ushort lB[2][BM * BK];
    const int tid  = threadIdx.x;
    const int lane = tid & 63, wid = tid >> 6;
    const int wr = wid >> 1, wc = wid & 1;
    const int l15 = lane & 15, lhi = lane >> 4;

    // decode linear tile id -> (rb, cb), cb >= rb   [S(rb) = rb*(257-rb)/2]
    const int t = blockIdx.x;
    float disc = 66049.0f - 8.0f * (float)t;        // 257^2 - 8t
    int rb = (int)((257.0f - sqrtf(disc)) * 0.5f);
    if (rb > NB - 1) rb = NB - 1;
    if (rb < 0) rb = 0;
    while (rb > 0 && rb * (257 - rb) / 2 > t) --rb;
    while ((rb + 1) * (257 - (rb + 1)) / 2 <= t) ++rb;
    const int cb = rb + (t - rb * (257 - rb) / 2);
    const int rowbase = rb * BM;
    const int colbase = cb * BM;
    const bool diag = (rb == cb);

    const int s_row  = tid >> 3;      // row within 32-row chunk
    const int s_slot = tid & 7;       // 8-elem slot within 64-elem row

    f32x4 acc[4][4];
    const f32x4 z = {0.f, 0.f, 0.f, 0.f};
#pragma unroll
    for (int i = 0; i < 4; ++i)
#pragma unroll
        for (int j = 0; j < 4; ++j) acc[i][j] = z;

    auto STAGE = [&](int buf, int kt) {
        // XOR-swizzled source so linear global_load_lds dest + swizzled
        // ds_read agree (slot' = slot ^ (row&7)); 4 issues of 32 rows each.
#pragma unroll
        for (int it = 0; it < 4; ++it) {
            const int r = it * 32 + s_row;
            const size_t koff = (size_t)kt * BK + (size_t)((s_slot ^ (r & 7)) << 3);
            const ushort* gA = Xn + (size_t)(rowbase + r) * DIM + koff;
            const ushort* gB = Xn + (size_t)(colbase + r) * DIM + koff;
            const ushort* dA = &lA[buf][it * 2048 + wid * 512];
            const ushort* dB = &lB[buf][it * 2048 + wid * 512];
            gload16(gA, dA);
            gload16(gB, dB);
        }
    };

    STAGE(0, 0);
    for (int kt = 0; kt < KT; ++kt) {
        __syncthreads();                       // buf[kt&1] ready
        if (kt + 1 < KT) STAGE((kt + 1) & 1, kt + 1);
        const ushort* A = lA[kt & 1];
        const ushort* B = lB[kt & 1];
#pragma unroll
        for (int ks = 0; ks < 2; ++ks) {
            f16x8 af[4], bg[4];
#pragma unroll
            for (int mf = 0; mf < 4; ++mf) {
                const int r = wr * 64 + mf * 16 + l15;
                const int slot = (ks * 4 + lhi) ^ (r & 7);
                af[mf] = *(const f16x8*)(A + r * BK + slot * 8);
            }
#pragma unroll
            for (int nf = 0; nf < 4; ++nf) {
                const int r = wc * 64 + nf * 16 + l15;
                const int slot = (ks * 4 + lhi) ^ (r & 7);
                bg[nf] = *(const f16x8*)(B + r * BK + slot * 8);
            }
#pragma unroll
            for (int mf = 0; mf < 4; ++mf)
#pragma unroll
                for (int nf = 0; nf < 4; ++nf)
                    acc[mf][nf] = __builtin_amdgcn_mfma_f32_16x16x32_f16(
                        af[mf], bg[nf], acc[mf][nf], 0, 0, 0);
        }
    }

    // diagonal tiles: mask self-similarity to -1 (reference semantics)
    if (diag) {
#pragma unroll
        for (int mf = 0; mf < 4; ++mf)
#pragma unroll
            for (int nf = 0; nf < 4; ++nf)
#pragma unroll
                for (int rr = 0; rr < 4; ++rr) {
                    const int rl = wr * 64 + mf * 16 + lhi * 4 + rr;
                    const int cl = wc * 64 + nf * 16 + l15;
                    if (rl == cl) acc[mf][nf][rr] = -1.0f;
                }
    }

    // ---- row-max: reduce over nf (regs) then 16 cols (lane bits 0..3) ----
#pragma unroll
    for (int mf = 0; mf < 4; ++mf) {
#pragma unroll
        for (int rr = 0; rr < 4; ++rr) {
            float v = fmaxf(fmaxf(acc[mf][0][rr], acc[mf][1][rr]),
                            fmaxf(acc[mf][2][rr], acc[mf][3][rr]));
            v = fmaxf(v, __shfl_xor(v, 1));
            v = fmaxf(v, __shfl_xor(v, 2));
            v = fmaxf(v, __shfl_xor(v, 4));
            v = fmaxf(v, __shfl_xor(v, 8));
            if (l15 == 0) {
                const int r = rowbase + wr * 64 + mf * 16 + lhi * 4 + rr;
                atomicMax(&nnkey[r], fkey(v));
            }
        }
    }

    // ---- col-max: reduce over mf,rr (regs) then 4 row-groups (bits 4,5) ----
#pragma unroll
    for (int nf = 0; nf < 4; ++nf) {
        float v = -2.0f;
#pragma unroll
        for (int mf = 0; mf < 4; ++mf)
#pragma unroll
            for (int rr = 0; rr < 4; ++rr) v = fmaxf(v, acc[mf][nf][rr]);
        v = fmaxf(v, __shfl_xor(v, 16));
        v = fmaxf(v, __shfl_xor(v, 32));
        if (lhi == 0) {
            const int c = colbase + wc * 64 + nf * 16 + l15;
            atomicMax(&nnkey[c], fkey(v));
        }
    }
}

// ---------------- Kernel 3: compute loss from nn-max keys --------------------
__global__ __launch_bounds__(256) void k_loss(const uint32_t* __restrict__ nnkey,
                                              float* __restrict__ out) {
    float local = 0.0f;
    for (int r = threadIdx.x; r < NR; r += 256) {
        const float m = unkey(nnkey[r]);
        const float d = sqrtf(fmaxf(2.0f - 2.0f * m, 0.0f));
        local += logf(d + KEPS);
    }
#pragma unroll
    for (int m = 32; m >= 1; m >>= 1) local += __shfl_xor(local, m);
    __shared__ float red[4];
    const int lane = threadIdx.x & 63, wid = threadIdx.x >> 6;
    if (lane == 0) red[wid] = local;
    __syncthreads();
    if (threadIdx.x == 0)
        out[0] = -(red[0] + red[1] + red[2] + red[3]) / (float)NR;
}

extern "C" void kernel_launch(void* const* d_in, const int* in_sizes, int n_in,
                              void* d_out, int out_size, void* d_ws, size_t ws_size,
                              hipStream_t stream) {
    const float* X = (const float*)d_in[0];
    float* out = (float*)d_out;
    ushort* Xn = (ushort*)d_ws;                                    // 24 MiB fp16
    uint32_t* nnkey = (uint32_t*)((char*)d_ws + (size_t)NR * DIM * 2); // 64 KiB

    k_norm<<<NR / 4, 256, 0, stream>>>(X, Xn);
    k_init<<<NR / 256, 256, 0, stream>>>(nnkey);
    k_maxdot<<<NTILES, 256, 0, stream>>>(Xn, nnkey);
    k_loss<<<1, 256, 0, stream>>>(nnkey, out);
}